// Round 1
// baseline (360.089 us; speedup 1.0000x reference)
//
#include <hip/hip_runtime.h>
#include <hip/hip_bf16.h>

// out[b,f] = -(sum_w x[b,w,f] * W[f,w] + bias[f])
// B=512, W_SIZE=5, F=25000.  F/4 = 6250 exactly -> float4 everywhere.

#define B_DIM 512
#define W_SIZE 5
#define F_DIM 25000
#define F4 (F_DIM / 4)   // 6250

__global__ __launch_bounds__(256) void ocsvm_kernel(
    const float* __restrict__ x,     // [B, W_SIZE, F]
    const float* __restrict__ W,     // [F, W_SIZE]
    const float* __restrict__ bias,  // [F]
    float* __restrict__ out)         // [B, F]
{
    const int f4 = blockIdx.x * blockDim.x + threadIdx.x;  // which float4 along F
    const int b  = blockIdx.y;
    if (f4 >= F4) return;

    const int f = f4 * 4;

    // bias for 4 consecutive f
    float4 acc = *reinterpret_cast<const float4*>(bias + f);

    // W rows for f..f+3: 20 contiguous floats, 16B-aligned (f*5*4 bytes, f%4==0)
    const float* wp = W + (size_t)f * W_SIZE;
    float4 w0 = *reinterpret_cast<const float4*>(wp + 0);   // f+0:w0..3
    float4 w1 = *reinterpret_cast<const float4*>(wp + 4);   // f+0:w4, f+1:w0..2
    float4 w2 = *reinterpret_cast<const float4*>(wp + 8);   // f+1:w3..4, f+2:w0..1
    float4 w3 = *reinterpret_cast<const float4*>(wp + 12);  // f+2:w2..4, f+3:w0
    float4 w4 = *reinterpret_cast<const float4*>(wp + 16);  // f+3:w1..4

    // per-f weight vectors, unpacked
    float wf0[5] = {w0.x, w0.y, w0.z, w0.w, w1.x};
    float wf1[5] = {w1.y, w1.z, w1.w, w2.x, w2.y};
    float wf2[5] = {w2.z, w2.w, w3.x, w3.y, w3.z};
    float wf3[5] = {w3.w, w4.x, w4.y, w4.z, w4.w};

    const float* xb = x + (size_t)b * (W_SIZE * F_DIM) + f;
#pragma unroll
    for (int w = 0; w < W_SIZE; ++w) {
        float4 xv = *reinterpret_cast<const float4*>(xb + (size_t)w * F_DIM);
        acc.x = fmaf(xv.x, wf0[w], acc.x);
        acc.y = fmaf(xv.y, wf1[w], acc.y);
        acc.z = fmaf(xv.z, wf2[w], acc.z);
        acc.w = fmaf(xv.w, wf3[w], acc.w);
    }

    float4 res;
    res.x = -acc.x; res.y = -acc.y; res.z = -acc.z; res.w = -acc.w;
    *reinterpret_cast<float4*>(out + (size_t)b * F_DIM + f) = res;
}

extern "C" void kernel_launch(void* const* d_in, const int* in_sizes, int n_in,
                              void* d_out, int out_size, void* d_ws, size_t ws_size,
                              hipStream_t stream) {
    const float* x    = (const float*)d_in[0];
    const float* W    = (const float*)d_in[1];
    const float* bias = (const float*)d_in[2];
    float* out = (float*)d_out;

    dim3 block(256);
    dim3 grid((F4 + 255) / 256, B_DIM);  // (25, 512)
    ocsvm_kernel<<<grid, block, 0, stream>>>(x, W, bias, out);
}

// Round 2
// 343.857 us; speedup vs baseline: 1.0472x; 1.0472x over previous
//
#include <hip/hip_runtime.h>
#include <hip/hip_bf16.h>

// out[b,f] = -(sum_w x[b,w,f] * W[f,w] + bias[f])
// B=512, W_SIZE=5, F=25000.  F/4 = 6250 exactly -> float4 everywhere.
// Each thread: one f-quad, BPT consecutive b values (reuses W/bias regs x BPT).

#define B_DIM 512
#define W_SIZE 5
#define F_DIM 25000
#define F4 (F_DIM / 4)   // 6250
#define BPT 8            // b values per thread

typedef float v4f __attribute__((ext_vector_type(4)));

__global__ __launch_bounds__(256) void ocsvm_kernel(
    const float* __restrict__ x,     // [B, W_SIZE, F]
    const float* __restrict__ W,     // [F, W_SIZE]
    const float* __restrict__ bias,  // [F]
    float* __restrict__ out)         // [B, F]
{
    const int f4 = blockIdx.x * blockDim.x + threadIdx.x;  // f-quad index
    if (f4 >= F4) return;
    const int f  = f4 * 4;
    const int b0 = blockIdx.y * BPT;

    // bias for 4 consecutive f (L2-resident, reused across all b)
    v4f bias4 = *reinterpret_cast<const v4f*>(bias + f);

    // W rows for f..f+3: 20 contiguous floats, 16B-aligned
    const float* wp = W + (size_t)f * W_SIZE;
    v4f w0 = *reinterpret_cast<const v4f*>(wp + 0);
    v4f w1 = *reinterpret_cast<const v4f*>(wp + 4);
    v4f w2 = *reinterpret_cast<const v4f*>(wp + 8);
    v4f w3 = *reinterpret_cast<const v4f*>(wp + 12);
    v4f w4 = *reinterpret_cast<const v4f*>(wp + 16);

    // per-f weight vectors (registers; indexed only by unrolled constants)
    const float wf0[5] = {w0.x, w0.y, w0.z, w0.w, w1.x};
    const float wf1[5] = {w1.y, w1.z, w1.w, w2.x, w2.y};
    const float wf2[5] = {w2.z, w2.w, w3.x, w3.y, w3.z};
    const float wf3[5] = {w3.w, w4.x, w4.y, w4.z, w4.w};

    const float* xb = x + (size_t)b0 * (W_SIZE * F_DIM) + f;
    float*       op = out + (size_t)b0 * F_DIM + f;

#pragma unroll
    for (int bb = 0; bb < BPT; ++bb) {
        const float* xrow = xb + (size_t)bb * (W_SIZE * F_DIM);
        v4f xv[W_SIZE];
#pragma unroll
        for (int w = 0; w < W_SIZE; ++w)
            xv[w] = __builtin_nontemporal_load(
                reinterpret_cast<const v4f*>(xrow + (size_t)w * F_DIM));

        v4f acc = bias4;
#pragma unroll
        for (int w = 0; w < W_SIZE; ++w) {
            acc.x = fmaf(xv[w].x, wf0[w], acc.x);
            acc.y = fmaf(xv[w].y, wf1[w], acc.y);
            acc.z = fmaf(xv[w].z, wf2[w], acc.z);
            acc.w = fmaf(xv[w].w, wf3[w], acc.w);
        }
        __builtin_nontemporal_store(-acc,
            reinterpret_cast<v4f*>(op + (size_t)bb * F_DIM));
    }
}

extern "C" void kernel_launch(void* const* d_in, const int* in_sizes, int n_in,
                              void* d_out, int out_size, void* d_ws, size_t ws_size,
                              hipStream_t stream) {
    const float* x    = (const float*)d_in[0];
    const float* W    = (const float*)d_in[1];
    const float* bias = (const float*)d_in[2];
    float* out = (float*)d_out;

    dim3 block(256);
    dim3 grid((F4 + 255) / 256, B_DIM / BPT);  // (25, 64)
    ocsvm_kernel<<<grid, block, 0, stream>>>(x, W, bias, out);
}

// Round 3
// 337.928 us; speedup vs baseline: 1.0656x; 1.0175x over previous
//
#include <hip/hip_runtime.h>
#include <hip/hip_bf16.h>

// out[b,f] = -(sum_w x[b,w,f] * W[f,w] + bias[f])
// B=512, W_SIZE=5, F=25000.  F/4 = 6250 exactly -> float4 everywhere.
// Each thread: one f-quad, BPT consecutive b values.
// BPT=4 -> grid (25,128) = 3200 blocks = 12.5 blocks/CU (tail quantization ~4%
// vs ~12% at BPT=8/1600 blocks), 20 outstanding 16B NT loads per thread.

#define B_DIM 512
#define W_SIZE 5
#define F_DIM 25000
#define F4 (F_DIM / 4)   // 6250
#define BPT 4            // b values per thread

typedef float v4f __attribute__((ext_vector_type(4)));

__global__ __launch_bounds__(256) void ocsvm_kernel(
    const float* __restrict__ x,     // [B, W_SIZE, F]
    const float* __restrict__ W,     // [F, W_SIZE]
    const float* __restrict__ bias,  // [F]
    float* __restrict__ out)         // [B, F]
{
    const int f4 = blockIdx.x * blockDim.x + threadIdx.x;  // f-quad index
    if (f4 >= F4) return;
    const int f  = f4 * 4;
    const int b0 = blockIdx.y * BPT;

    // bias for 4 consecutive f (L2-resident, reused across all b)
    v4f bias4 = *reinterpret_cast<const v4f*>(bias + f);

    // W rows for f..f+3: 20 contiguous floats, 16B-aligned
    const float* wp = W + (size_t)f * W_SIZE;
    v4f w0 = *reinterpret_cast<const v4f*>(wp + 0);
    v4f w1 = *reinterpret_cast<const v4f*>(wp + 4);
    v4f w2 = *reinterpret_cast<const v4f*>(wp + 8);
    v4f w3 = *reinterpret_cast<const v4f*>(wp + 12);
    v4f w4 = *reinterpret_cast<const v4f*>(wp + 16);

    // per-f weight vectors (registers; indexed only by unrolled constants)
    const float wf0[5] = {w0.x, w0.y, w0.z, w0.w, w1.x};
    const float wf1[5] = {w1.y, w1.z, w1.w, w2.x, w2.y};
    const float wf2[5] = {w2.z, w2.w, w3.x, w3.y, w3.z};
    const float wf3[5] = {w3.w, w4.x, w4.y, w4.z, w4.w};

    const float* xb = x + (size_t)b0 * (W_SIZE * F_DIM) + f;
    float*       op = out + (size_t)b0 * F_DIM + f;

#pragma unroll
    for (int bb = 0; bb < BPT; ++bb) {
        const float* xrow = xb + (size_t)bb * (W_SIZE * F_DIM);
        v4f xv[W_SIZE];
#pragma unroll
        for (int w = 0; w < W_SIZE; ++w)
            xv[w] = __builtin_nontemporal_load(
                reinterpret_cast<const v4f*>(xrow + (size_t)w * F_DIM));

        v4f acc = bias4;
#pragma unroll
        for (int w = 0; w < W_SIZE; ++w) {
            acc.x = fmaf(xv[w].x, wf0[w], acc.x);
            acc.y = fmaf(xv[w].y, wf1[w], acc.y);
            acc.z = fmaf(xv[w].z, wf2[w], acc.z);
            acc.w = fmaf(xv[w].w, wf3[w], acc.w);
        }
        __builtin_nontemporal_store(-acc,
            reinterpret_cast<v4f*>(op + (size_t)bb * F_DIM));
    }
}

extern "C" void kernel_launch(void* const* d_in, const int* in_sizes, int n_in,
                              void* d_out, int out_size, void* d_ws, size_t ws_size,
                              hipStream_t stream) {
    const float* x    = (const float*)d_in[0];
    const float* W    = (const float*)d_in[1];
    const float* bias = (const float*)d_in[2];
    float* out = (float*)d_out;

    dim3 block(256);
    dim3 grid((F4 + 255) / 256, B_DIM / BPT);  // (25, 128)
    ocsvm_kernel<<<grid, block, 0, stream>>>(x, W, bias, out);
}